// Round 20
// baseline (195.943 us; speedup 1.0000x reference)
//
#include <hip/hip_runtime.h>
#include <math.h>

#define D_    256
#define NE    512
#define NNODE 64
#define NHEAD 4
#define SLOPE 0.2f
#define BTN   65536

typedef __attribute__((ext_vector_type(4))) float f32x4;
typedef __attribute__((ext_vector_type(8))) _Float16 f16x8;
typedef __attribute__((ext_vector_type(2))) _Float16 f16x2;
typedef __attribute__((ext_vector_type(2))) __fp16   h16x2;   // builtin interop
typedef unsigned short u16;

__device__ inline u16 f2h(float x) {
    union { _Float16 h; u16 u; } v; v.h = (_Float16)x; return v.u;
}
__device__ inline f16x2 pkrtz(float lo, float hi) {
    h16x2 r = __builtin_amdgcn_cvt_pkrtz(lo, hi);
    f16x2 o; __builtin_memcpy(&o, &r, 4); return o;
}
__device__ inline f16x8 pack8(float4 v0, float4 v1) {
    f16x2 a = pkrtz(v0.x, v0.y), b = pkrtz(v0.z, v0.w);
    f16x2 c = pkrtz(v1.x, v1.y), d = pkrtz(v1.z, v1.w);
    f16x8 o;
    __builtin_memcpy(&o, &a, 4);
    __builtin_memcpy((char*)&o + 4, &b, 4);
    __builtin_memcpy((char*)&o + 8, &c, 4);
    __builtin_memcpy((char*)&o + 12, &d, 4);
    return o;
}

#define GLD16(g, l) __builtin_amdgcn_global_load_lds( \
    (const __attribute__((address_space(1))) void*)(g), \
    (__attribute__((address_space(3))) void*)(l), 16, 0, 0)

// ---------------------------------------------------------------------------
// Edge table: pack (src<<8)|dst and log(A0+eps) into one int2. One block.
// ---------------------------------------------------------------------------
__global__ __launch_bounds__(512) void build_edge(const int* __restrict__ src,
    const int* __restrict__ dst, const float* __restrict__ A0,
    int2* __restrict__ gedge)
{
    const int t = threadIdx.x;
    int s = src[t], d = dst[t];
    float lg = logf(A0[s * NNODE + d] + 1e-8f);
    gedge[t] = make_int2((s << 8) | d, __float_as_int(lg));
}

// Three 256x256 weights -> fp16 in one launch (192 blocks).
__global__ __launch_bounds__(256) void prep_w3(const float* __restrict__ w0,
    const float* __restrict__ w1, const float* __restrict__ w2,
    u16* __restrict__ h0, u16* __restrict__ h1, u16* __restrict__ h2)
{
    int sel = blockIdx.x >> 6, b = blockIdx.x & 63;
    const float* s = sel == 0 ? w0 : sel == 1 ? w1 : w2;
    u16* h = sel == 0 ? h0 : sel == 1 ? h1 : h2;
    int i = b * 256 + threadIdx.x;
    float4 v = ((const float4*)s)[i];
    ((ushort4*)h)[i] = make_ushort4(f2h(v.x), f2h(v.y), f2h(v.z), f2h(v.w));
}

// ---------------------------------------------------------------------------
// MEGA-FUSED: per (bt, head) block computes Q-slice and V^T-slice GEMMs
// in-LDS (H staged once, weights read as fragments from L2-resident fp16),
// then edge scores (MFMA) + segment softmax + P-build + PV (MFMA) -> Yh.
// No Xq/Xv materialization: saves 128MB HBM + prep_hi + 2 kernel launches.
// LDS 48KB: sH 32KB (-> sP/tables after GEMMs) | sQ 8KB | sVt 8KB.
// 3 blocks/CU, 12 waves.
// ---------------------------------------------------------------------------
__global__ __launch_bounds__(256, 3) void fused_all(
    const float* __restrict__ H, const u16* __restrict__ Wlh,
    const u16* __restrict__ Wvh, const int2* __restrict__ gedge,
    const float* __restrict__ a, u16* __restrict__ Yh)
{
    __shared__ u16 smem[24576];                 // 48 KB
    u16*   sH    = smem;                        // [64][256] fp16, swizzled (32KB)
    float* sP    = (float*)smem;                // 16KB, aliases dead sH
    float* sBn   = (float*)(smem + 8192);       // 64 f
    float* sLin  = (float*)(smem + 8320);       // 512 f
    int*   sPack = (int*)(smem + 9344);         // 512 i
    u16*   sQ    = smem + 16384;                // [node][dim] 8KB; later P fp16
    u16*   sVt   = smem + 20480;                // [dim][node] 8KB

    const int t = threadIdx.x, lane = t & 63, wave = t >> 6;
    const int fr = lane & 15, qtr = lane >> 4, fq = qtr * 4;
    const int bid = blockIdx.x;
    const int swz = (bid & 7) * 512 + (bid >> 3);   // 4 siblings same XCD
    const int bt = swz >> 2, h = swz & 3;

    // ---- B-fragments for the score MFMA: 0.4*a, replicated rows ----
    f16x8 af[2];
    #pragma unroll
    for (int kk = 0; kk < 2; ++kk) {
        const float* ab = a + h * 64 + kk * 32 + qtr * 8;
        float4 a0 = *(const float4*)ab, a1 = *(const float4*)(ab + 4);
        af[kk][0] = (_Float16)(0.4f * a0.x); af[kk][1] = (_Float16)(0.4f * a0.y);
        af[kk][2] = (_Float16)(0.4f * a0.z); af[kk][3] = (_Float16)(0.4f * a0.w);
        af[kk][4] = (_Float16)(0.4f * a1.x); af[kk][5] = (_Float16)(0.4f * a1.y);
        af[kk][6] = (_Float16)(0.4f * a1.z); af[kk][7] = (_Float16)(0.4f * a1.w);
    }

    // ---- stage H[bt] fp32 -> fp16 into sH, chunk swizzle c^=(node&7) ----
    // 2048 16B-chunks; thread does 8. Chunk ch: node=ch>>5, c=ch&31.
    const float* hp = H + (size_t)bt * (NNODE * D_);
    #pragma unroll
    for (int i = 0; i < 8; ++i) {
        int ch = i * 256 + t;
        int node = ch >> 5, c = ch & 31;
        const float* p = hp + node * 256 + c * 8;
        float4 v0 = *(const float4*)p;
        float4 v1 = *(const float4*)(p + 4);
        int cs = (c & 24) | ((c ^ node) & 7);
        *(f16x8*)&sH[node * 256 + cs * 8] = pack8(v0, v1);
    }
    __syncthreads();

    // ---- Q-GEMM: wave w -> nodes [w*16, w*16+16), dims [h*64, h*64+64) ----
    const int anode = wave * 16 + fr;
    f32x4 acc4[4];
    #pragma unroll
    for (int i = 0; i < 4; ++i) acc4[i] = 0.f;
    #pragma unroll
    for (int ks = 0; ks < 8; ++ks) {
        int c = ks * 4 + qtr;
        int cs = (c & 24) | ((c ^ anode) & 7);
        f16x8 fa = *(const f16x8*)&sH[anode * 256 + cs * 8];
        #pragma unroll
        for (int ni = 0; ni < 4; ++ni) {
            f16x8 fb = *(const f16x8*)&Wlh[(size_t)(h * 64 + ni * 16 + fr) * 256
                                           + ks * 32 + qtr * 8];
            acc4[ni] = __builtin_amdgcn_mfma_f32_16x16x32_f16(fa, fb, acc4[ni], 0, 0, 0);
        }
    }
    // epilogue -> sQ [node][dim], chunk^=(node&7)
    #pragma unroll
    for (int ni = 0; ni < 4; ++ni)
        #pragma unroll
        for (int r = 0; r < 4; ++r) {
            int node = wave * 16 + fq + r;
            int dim  = ni * 16 + fr;
            sQ[node * 64 + (((dim >> 3) ^ (node & 7)) << 3) + (dim & 7)]
                = f2h(acc4[ni][r]);
        }

    // ---- V-GEMM: same A-frags, B = W_val; epilogue -> sVt [dim][node] ----
    #pragma unroll
    for (int i = 0; i < 4; ++i) acc4[i] = 0.f;
    #pragma unroll
    for (int ks = 0; ks < 8; ++ks) {
        int c = ks * 4 + qtr;
        int cs = (c & 24) | ((c ^ anode) & 7);
        f16x8 fa = *(const f16x8*)&sH[anode * 256 + cs * 8];
        #pragma unroll
        for (int ni = 0; ni < 4; ++ni) {
            f16x8 fb = *(const f16x8*)&Wvh[(size_t)(h * 64 + ni * 16 + fr) * 256
                                           + ks * 32 + qtr * 8];
            acc4[ni] = __builtin_amdgcn_mfma_f32_16x16x32_f16(fa, fb, acc4[ni], 0, 0, 0);
        }
    }
    {
        int node0 = wave * 16 + fq;
        #pragma unroll
        for (int ni = 0; ni < 4; ++ni) {
            int dim = ni * 16 + fr;
            ushort4 v = make_ushort4(f2h(acc4[ni][0]), f2h(acc4[ni][1]),
                                     f2h(acc4[ni][2]), f2h(acc4[ni][3]));
            *(ushort4*)&sVt[dim * 64 + (((node0 >> 3) ^ (dim & 7)) << 3) + (node0 & 7)] = v;
        }
    }
    __syncthreads();   // sH dead; sQ/sVt complete

    // ---- zero sP (over dead sH) + b[n] = <q_n, a> ----
    #pragma unroll
    for (int i = 0; i < 4; ++i)
        ((float4*)sP)[t + i * 256] = make_float4(0.f, 0.f, 0.f, 0.f);
    {
        int n = t >> 2, qq = t & 3;
        float b = 0.f;
        #pragma unroll
        for (int j = 0; j < 2; ++j) {
            int ck = qq * 2 + j;
            f16x8 qv = *(const f16x8*)&sQ[n * 64 + ((ck ^ (n & 7)) << 3)];
            const float* ab = a + h * 64 + ck * 8;
            float4 a0 = *(const float4*)ab, a1 = *(const float4*)(ab + 4);
            b = fmaf((float)qv[0], a0.x, b); b = fmaf((float)qv[1], a0.y, b);
            b = fmaf((float)qv[2], a0.z, b); b = fmaf((float)qv[3], a0.w, b);
            b = fmaf((float)qv[4], a1.x, b); b = fmaf((float)qv[5], a1.y, b);
            b = fmaf((float)qv[6], a1.z, b); b = fmaf((float)qv[7], a1.w, b);
        }
        b += __shfl_xor(b, 1);
        b += __shfl_xor(b, 2);
        if (qq == 0) sBn[n] = b;
    }
    __syncthreads();

    // ---- edge tables: sPack + hoisted linear term (r14-proven form) ----
    #pragma unroll
    for (int i = 0; i < 2; ++i) {
        int e = t + i * 256;
        int2 ge = gedge[e];
        int s_ = ge.x >> 8, d_ = ge.x & 255;
        sPack[e] = ge.x;
        sLin[e] = 0.6f * (sBn[s_] + sBn[d_]) + __int_as_float(ge.y);
    }
    __syncthreads();

    // ---- edge pass: 8 tiles/wave x 16 edges, scores via MFMA ----
    const int wbase = wave * 128;
    #pragma unroll
    for (int tt = 0; tt < 8; ++tt) {
        int e = wbase + tt * 16 + fr;
        int pk = sPack[e];
        int s_ = pk >> 8, d_ = pk & 255;
        f32x4 acc = 0.f;
        #pragma unroll
        for (int kk = 0; kk < 2; ++kk) {
            int ck = kk * 4 + qtr;
            f16x8 qs = *(const f16x8*)&sQ[s_ * 64 + ((ck ^ (s_ & 7)) << 3)];
            f16x8 qd = *(const f16x8*)&sQ[d_ * 64 + ((ck ^ (d_ & 7)) << 3)];
            f16x8 x = qs + qd;
            unsigned xu[4];
            __builtin_memcpy(xu, &x, 16);
            xu[0] &= 0x7FFF7FFFu; xu[1] &= 0x7FFF7FFFu;
            xu[2] &= 0x7FFF7FFFu; xu[3] &= 0x7FFF7FFFu;
            f16x8 xa;
            __builtin_memcpy(&xa, xu, 16);
            acc = __builtin_amdgcn_mfma_f32_16x16x32_f16(xa, af[kk], acc, 0, 0, 0);
        }
        int c = lane & 15;
        if (c < 4) {
            float av = c == 0 ? acc[0] : c == 1 ? acc[1] : c == 2 ? acc[2] : acc[3];
            int eg = wbase + tt * 16 + qtr * 4 + c;
            int pk2 = sPack[eg];
            atomicAdd(&sP[(pk2 >> 8) * 64 + (pk2 & 255)], __expf(av + sLin[eg]));
        }
    }
    __syncthreads();

    // ---- convert: row-sum -> denom; normalize; fp16 into dead sQ (swizzled) ----
    {
        int s_ = t >> 2, qq = t & 3;
        const float4* row = (const float4*)&sP[s_ * 64 + qq * 16];
        float4 v0 = row[0], v1 = row[1], v2 = row[2], v3 = row[3];
        float part = v0.x + v0.y + v0.z + v0.w + v1.x + v1.y + v1.z + v1.w
                   + v2.x + v2.y + v2.z + v2.w + v3.x + v3.y + v3.z + v3.w;
        part += __shfl_xor(part, 1);
        part += __shfl_xor(part, 2);
        float inv = part > 0.f ? 1.f / part : 0.f;
        f16x2 p0 = pkrtz(v0.x * inv, v0.y * inv), p1 = pkrtz(v0.z * inv, v0.w * inv);
        f16x2 p2 = pkrtz(v1.x * inv, v1.y * inv), p3 = pkrtz(v1.z * inv, v1.w * inv);
        f16x2 p4 = pkrtz(v2.x * inv, v2.y * inv), p5 = pkrtz(v2.z * inv, v2.w * inv);
        f16x2 p6 = pkrtz(v3.x * inv, v3.y * inv), p7 = pkrtz(v3.z * inv, v3.w * inv);
        int c0 = qq * 2, c1 = qq * 2 + 1;
        u16* d0 = &sQ[s_ * 64 + ((c0 ^ (s_ & 7)) << 3)];
        u16* d1 = &sQ[s_ * 64 + ((c1 ^ (s_ & 7)) << 3)];
        ((f16x2*)d0)[0] = p0; ((f16x2*)d0)[1] = p1;
        ((f16x2*)d0)[2] = p2; ((f16x2*)d0)[3] = p3;
        ((f16x2*)d1)[0] = p4; ((f16x2*)d1)[1] = p5;
        ((f16x2*)d1)[2] = p6; ((f16x2*)d1)[3] = p7;
    }
    __syncthreads();

    // ---- Y^T = V^T · P^T : wave owns 16 src nodes; 8 MFMAs (A from sVt) ----
    f32x4 acc[4];
    #pragma unroll
    for (int i = 0; i < 4; ++i) acc[i] = 0.f;
    const int srow = wave * 16 + fr;
    #pragma unroll
    for (int kk = 0; kk < 2; ++kk) {
        int g = kk * 4 + qtr;
        f16x8 fb = *(const f16x8*)&sQ[srow * 64 + ((g ^ (srow & 7)) << 3)];
        #pragma unroll
        for (int mi = 0; mi < 4; ++mi) {
            int arow = mi * 16 + fr;
            f16x8 fa = *(const f16x8*)&sVt[arow * 64 + ((g ^ (arow & 7)) << 3)];
            acc[mi] = __builtin_amdgcn_mfma_f32_16x16x32_f16(fa, fb, acc[mi], 0, 0, 0);
        }
    }

    // ---- store: col = src node, row = dim ----
    const int node = wave * 16 + fr;
    u16* yh = Yh + ((size_t)bt * NNODE + node) * D_ + h * 64;
    #pragma unroll
    for (int mi = 0; mi < 4; ++mi) {
        ushort4 v = make_ushort4(f2h(acc[mi][0]), f2h(acc[mi][1]),
                                 f2h(acc[mi][2]), f2h(acc[mi][3]));
        *(ushort4*)&yh[mi * 16 + fq] = v;
    }
}

// ---------------------------------------------------------------------------
// GEMM3: out = Yh(fp16) x W_out^T(fp16), fp32 out. Single-buffered GLD16
// (measured ~5.6 TB/s — near HBM floor).
// ---------------------------------------------------------------------------
__global__ __launch_bounds__(256) void gemm3(const u16* __restrict__ A,
    const u16* __restrict__ B, float* __restrict__ Cout)
{
    __shared__ u16 sA[4096], sB[4096];
    const int t = threadIdx.x, lane = t & 63, wave = t >> 6;
    const int wm = wave >> 1, wn = wave & 1;
    const int bid = blockIdx.x;
    const int swz = (bid & 7) * 128 + (bid >> 3);
    const int m0 = (swz >> 1) * 128, n0 = (swz & 1) * 128;
    const int fr = lane & 15, kq = (lane >> 4) * 8;

    f32x4 acc[4][4];
    #pragma unroll
    for (int i = 0; i < 4; ++i)
        #pragma unroll
        for (int j = 0; j < 4; ++j) acc[i][j] = 0.f;

    for (int k0 = 0; k0 < D_; k0 += 32) {
        #pragma unroll
        for (int s = 0; s < 2; ++s) {
            const int cb = (s * 4 + wave) * 64;
            const int c  = cb + lane;
            const int row = c >> 2, ks = (c & 3) * 8;
            GLD16(A + (size_t)(m0 + row) * D_ + k0 + ks, sA + cb * 8);
            GLD16(B + (size_t)(n0 + row) * D_ + k0 + ks, sB + cb * 8);
        }
        __syncthreads();

        f16x8 fa[4];
        #pragma unroll
        for (int mi = 0; mi < 4; ++mi)
            fa[mi] = *(const f16x8*)(sA + (wm * 64 + mi * 16 + fr) * 32 + kq);
        #pragma unroll
        for (int ni = 0; ni < 4; ++ni) {
            f16x8 fb = *(const f16x8*)(sB + (wn * 64 + ni * 16 + fr) * 32 + kq);
            #pragma unroll
            for (int mi = 0; mi < 4; ++mi)
                acc[mi][ni] = __builtin_amdgcn_mfma_f32_16x16x32_f16(fa[mi], fb, acc[mi][ni], 0, 0, 0);
        }
        __syncthreads();
    }

    const int fq = (lane >> 4) * 4;
    #pragma unroll
    for (int mi = 0; mi < 4; ++mi)
        #pragma unroll
        for (int ni = 0; ni < 4; ++ni)
            #pragma unroll
            for (int r = 0; r < 4; ++r) {
                int m = m0 + wm * 64 + mi * 16 + fq + r;
                int n = n0 + wn * 64 + ni * 16 + fr;
                Cout[(size_t)m * D_ + n] = acc[mi][ni][r];
            }
}

// ---------------------------------------------------------------------------
extern "C" void kernel_launch(void* const* d_in, const int* in_sizes, int n_in,
                              void* d_out, int out_size, void* d_ws, size_t ws_size,
                              hipStream_t stream)
{
    const float* H     = (const float*)d_in[0];
    const float* W_lin = (const float*)d_in[1];
    const float* W_val = (const float*)d_in[2];
    const float* a     = (const float*)d_in[3];
    const float* W_out = (const float*)d_in[4];
    const float* A0    = (const float*)d_in[5];
    const int*   src   = (const int*)d_in[6];
    const int*   dst   = (const int*)d_in[7];

    const size_t nX = (size_t)BTN * D_;              // 16777216 elems
    // ws layout: Yh [0,32M) | Wlh | Wvh | Wouth | gedge
    u16*  Yh    = (u16*)d_ws;
    u16*  Wlh   = Yh + nX;
    u16*  Wvh   = Wlh + D_ * D_;
    u16*  Wouth = Wvh + D_ * D_;
    int2* gedge = (int2*)(Wouth + D_ * D_);
    if (ws_size < (size_t)(nX * 2 + 3 * D_ * D_ * 2 + NE * 8)) return;

    build_edge<<<1, 512, 0, stream>>>(src, dst, A0, gedge);
    prep_w3<<<192, 256, 0, stream>>>(W_lin, W_val, W_out, Wlh, Wvh, Wouth);

    fused_all<<<4096, 256, 0, stream>>>(H, Wlh, Wvh, gedge, a, Yh);

    gemm3<<<1024, 256, 0, stream>>>(Yh, Wouth, (float*)d_out);
}

// Round 22
// 104.624 us; speedup vs baseline: 1.8728x; 1.8728x over previous
//
#include <hip/hip_runtime.h>
#include <math.h>

#define D_    256
#define NE    512
#define NNODE 64
#define NHEAD 4
#define SLOPE 0.2f
#define BTN   65536

typedef __attribute__((ext_vector_type(4))) float f32x4;
typedef __attribute__((ext_vector_type(8))) _Float16 f16x8;
typedef __attribute__((ext_vector_type(2))) _Float16 f16x2;
typedef __attribute__((ext_vector_type(2))) __fp16   h16x2;   // builtin interop
typedef unsigned short u16;

__device__ inline u16 f2h(float x) {
    union { _Float16 h; u16 u; } v; v.h = (_Float16)x; return v.u;
}
__device__ inline f16x2 pkrtz(float lo, float hi) {
    h16x2 r = __builtin_amdgcn_cvt_pkrtz(lo, hi);
    f16x2 o; __builtin_memcpy(&o, &r, 4); return o;
}
__device__ inline f16x8 pack8(float4 v0, float4 v1) {
    f16x2 a = pkrtz(v0.x, v0.y), b = pkrtz(v0.z, v0.w);
    f16x2 c = pkrtz(v1.x, v1.y), d = pkrtz(v1.z, v1.w);
    f16x8 o;
    __builtin_memcpy(&o, &a, 4);
    __builtin_memcpy((char*)&o + 4, &b, 4);
    __builtin_memcpy((char*)&o + 8, &c, 4);
    __builtin_memcpy((char*)&o + 12, &d, 4);
    return o;
}

#define GLD16(g, l) __builtin_amdgcn_global_load_lds( \
    (const __attribute__((address_space(1))) void*)(g), \
    (__attribute__((address_space(3))) void*)(l), 16, 0, 0)

// ---------------------------------------------------------------------------
// Edge table: pack (src<<8)|dst and log(A0+eps) into one int2. One block.
// ---------------------------------------------------------------------------
__global__ __launch_bounds__(512) void build_edge(const int* __restrict__ src,
    const int* __restrict__ dst, const float* __restrict__ A0,
    int2* __restrict__ gedge)
{
    const int t = threadIdx.x;
    int s = src[t], d = dst[t];
    float lg = logf(A0[s * NNODE + d] + 1e-8f);
    gedge[t] = make_int2((s << 8) | d, __float_as_int(lg));
}

// Three 256x256 weights -> fp16 in one launch (192 blocks).
__global__ __launch_bounds__(256) void prep_w3(const float* __restrict__ w0,
    const float* __restrict__ w1, const float* __restrict__ w2,
    u16* __restrict__ h0, u16* __restrict__ h1, u16* __restrict__ h2)
{
    int sel = blockIdx.x >> 6, b = blockIdx.x & 63;
    const float* s = sel == 0 ? w0 : sel == 1 ? w1 : w2;
    u16* h = sel == 0 ? h0 : sel == 1 ? h1 : h2;
    int i = b * 256 + threadIdx.x;
    float4 v = ((const float4*)s)[i];
    ((ushort4*)h)[i] = make_ushort4(f2h(v.x), f2h(v.y), f2h(v.z), f2h(v.w));
}

// ---------------------------------------------------------------------------
// Fused GEMM1+2: [Xq|Xv] = H(fp32) x [W_lin|W_val]^T(fp16, 512 rows).
// BOTH operands staged via GLD16 (zero staging VALU): A as raw fp32 16KB
// (source chunk pre-swizzled csrc = c^(row&7), linear LDS dest — rule #21),
// B fp16 8KB linear. A fragments converted fp32->fp16 at read (pkrtz).
// smem 32KB = max(loop 24KB, epilogue bounce 4 waves x 8KB) — round-9/21
// lesson: the bounce needs the FULL 32KB. 5 blocks/CU.
// Epilogue: nq 0,1 -> Q slices [node][dim] chunk^=(node&7);
//           nq 2,3 -> V^T slices [dim][node] chunk^=(dim&7).
// ---------------------------------------------------------------------------
__global__ __launch_bounds__(256) void gemm12(const float* __restrict__ A32,
    const u16* __restrict__ B, u16* __restrict__ Xqh, u16* __restrict__ Xvt)
{
    __shared__ char smem[32768];                     // 32 KB
    float* sAf = (float*)smem;                       // [128][32] fp32 (16KB)
    u16*   sB  = (u16*)(smem + 16384);               // [128][32] fp16 (8KB)
    const int t = threadIdx.x, lane = t & 63, wave = t >> 6;
    const int wm = wave >> 1, wn = wave & 1;
    const int bid = blockIdx.x;
    const int swz = (bid & 7) * 256 + (bid >> 3);    // XCD-contiguous, bijective
    const int m0 = (swz >> 2) * 128, nq = swz & 3, n0 = nq * 128;
    const int fr = lane & 15, qtr = lane >> 4, kq = qtr * 8;

    f32x4 acc[4][4];
    #pragma unroll
    for (int i = 0; i < 4; ++i)
        #pragma unroll
        for (int j = 0; j < 4; ++j) acc[i][j] = 0.f;

    for (int k0 = 0; k0 < D_; k0 += 32) {
        // ---- A: 1024 16B fp32 chunks, source pre-swizzled, dest linear ----
        #pragma unroll
        for (int i = 0; i < 4; ++i) {
            int ch = i * 256 + t;
            int row = ch >> 3, c = ch & 7;
            int csrc = c ^ (row & 7);
            GLD16(A32 + (size_t)(m0 + row) * D_ + k0 + csrc * 4,
                  (char*)sAf + ch * 16);
        }
        // ---- B: 512 16B fp16 chunks, linear ----
        #pragma unroll
        for (int s = 0; s < 2; ++s) {
            const int cb = (s * 4 + wave) * 64;
            const int c  = cb + lane;
            const int row = c >> 2, ks = (c & 3) * 8;
            GLD16(B + (size_t)(n0 + row) * D_ + k0 + ks, sB + cb * 8);
        }
        __syncthreads();

        // ---- A fragments: swizzled fp32 read + convert ----
        f16x8 fa[4];
        #pragma unroll
        for (int mi = 0; mi < 4; ++mi) {
            int row = wm * 64 + mi * 16 + fr;
            int c0 = (2 * qtr)     ^ (row & 7);
            int c1 = (2 * qtr + 1) ^ (row & 7);
            float4 lo = *(const float4*)&sAf[row * 32 + c0 * 4];
            float4 hi = *(const float4*)&sAf[row * 32 + c1 * 4];
            fa[mi] = pack8(lo, hi);
        }
        #pragma unroll
        for (int ni = 0; ni < 4; ++ni) {
            f16x8 fb = *(const f16x8*)(sB + (wn * 64 + ni * 16 + fr) * 32 + kq);
            #pragma unroll
            for (int mi = 0; mi < 4; ++mi)
                acc[mi][ni] = __builtin_amdgcn_mfma_f32_16x16x32_f16(fa[mi], fb, acc[mi][ni], 0, 0, 0);
        }
        __syncthreads();
    }

    // ---- epilogue: wave quadrant = one (bt,h) 64x64 slice; bounce = full smem
    const int fq = qtr * 4;           // C/D: col = lane&15, row = (lane>>4)*4 + reg
    u16* wT = (u16*)smem + wave * 4096;
    const bool isQ = nq < 2;
    #pragma unroll
    for (int mi = 0; mi < 4; ++mi)
        #pragma unroll
        for (int ni = 0; ni < 4; ++ni) {
            int node0 = mi * 16 + fq;              // r = 0..3 consecutive nodes
            int dim   = ni * 16 + fr;
            if (!isQ) {                            // V^T: [dim][node], chunk^=dim&7
                ushort4 v = make_ushort4(f2h(acc[mi][ni][0]), f2h(acc[mi][ni][1]),
                                         f2h(acc[mi][ni][2]), f2h(acc[mi][ni][3]));
                *(ushort4*)&wT[dim * 64 + (((node0 >> 3) ^ (dim & 7)) << 3) + (node0 & 7)] = v;
            } else {                               // Q: [node][dim], chunk^=node&7
                #pragma unroll
                for (int r = 0; r < 4; ++r) {
                    int node = node0 + r;
                    wT[node * 64 + ((((dim >> 3) ^ (node & 7))) << 3) + (dim & 7)]
                        = f2h(acc[mi][ni][r]);
                }
            }
        }
    __syncthreads();
    const int btq = (m0 >> 6) + wm;
    const int hq  = isQ ? (n0 >> 6) + wn : ((n0 - 256) >> 6) + wn;
    u16* gx = (isQ ? Xqh : Xvt) + ((size_t)btq * NHEAD + hq) * 4096;
    #pragma unroll
    for (int r = 0; r < 8; ++r)
        *(f16x8*)&gx[r * 512 + lane * 8] = *(const f16x8*)&wT[r * 512 + lane * 8];
}

// ---------------------------------------------------------------------------
// GEMM3: out = Yh(fp16) x W_out^T(fp16), fp32 out. Single-buffered GLD16
// (measured ~5.6 TB/s — near HBM floor).
// ---------------------------------------------------------------------------
__global__ __launch_bounds__(256) void gemm3(const u16* __restrict__ A,
    const u16* __restrict__ B, float* __restrict__ Cout)
{
    __shared__ u16 sA[4096], sB[4096];
    const int t = threadIdx.x, lane = t & 63, wave = t >> 6;
    const int wm = wave >> 1, wn = wave & 1;
    const int bid = blockIdx.x;
    const int swz = (bid & 7) * 128 + (bid >> 3);
    const int m0 = (swz >> 1) * 128, n0 = (swz & 1) * 128;
    const int fr = lane & 15, kq = (lane >> 4) * 8;

    f32x4 acc[4][4];
    #pragma unroll
    for (int i = 0; i < 4; ++i)
        #pragma unroll
        for (int j = 0; j < 4; ++j) acc[i][j] = 0.f;

    for (int k0 = 0; k0 < D_; k0 += 32) {
        #pragma unroll
        for (int s = 0; s < 2; ++s) {
            const int cb = (s * 4 + wave) * 64;
            const int c  = cb + lane;
            const int row = c >> 2, ks = (c & 3) * 8;
            GLD16(A + (size_t)(m0 + row) * D_ + k0 + ks, sA + cb * 8);
            GLD16(B + (size_t)(n0 + row) * D_ + k0 + ks, sB + cb * 8);
        }
        __syncthreads();

        f16x8 fa[4];
        #pragma unroll
        for (int mi = 0; mi < 4; ++mi)
            fa[mi] = *(const f16x8*)(sA + (wm * 64 + mi * 16 + fr) * 32 + kq);
        #pragma unroll
        for (int ni = 0; ni < 4; ++ni) {
            f16x8 fb = *(const f16x8*)(sB + (wn * 64 + ni * 16 + fr) * 32 + kq);
            #pragma unroll
            for (int mi = 0; mi < 4; ++mi)
                acc[mi][ni] = __builtin_amdgcn_mfma_f32_16x16x32_f16(fa[mi], fb, acc[mi][ni], 0, 0, 0);
        }
        __syncthreads();
    }

    const int fq = (lane >> 4) * 4;
    #pragma unroll
    for (int mi = 0; mi < 4; ++mi)
        #pragma unroll
        for (int ni = 0; ni < 4; ++ni)
            #pragma unroll
            for (int r = 0; r < 4; ++r) {
                int m = m0 + wm * 64 + mi * 16 + fq + r;
                int n = n0 + wn * 64 + ni * 16 + fr;
                Cout[(size_t)m * D_ + n] = acc[mi][ni][r];
            }
}

// ---------------------------------------------------------------------------
// Fused edge scores + softmax + aggregation (r14-measured-best version):
// MFMA edge scores, sPack/sLin tables, edge-parallel atomics, MFMA PV.
// LDS ~28.9KB, launch_bounds (256,5).
// ---------------------------------------------------------------------------
__global__ __launch_bounds__(256, 5) void fused_edge_agg(
    const u16* __restrict__ Xqh, const u16* __restrict__ Xvt,
    const int2* __restrict__ gedge, const float* __restrict__ a,
    u16* __restrict__ Yh)
{
    __shared__ u16   sQ[4096];    // 8 KB  Q fp16 swizzled; later P fp16 (swz)
    __shared__ float sP[4096];    // 16 KB P f32 [src][dst]
    __shared__ float sBn[NNODE];  // b[n] = <q_n, a>
    __shared__ float sLin[NE];    // 0.6*(b_s+b_d) + logA0
    __shared__ int   sPack[NE];   // (src<<8)|dst

    const int t = threadIdx.x, lane = t & 63, wave = t >> 6;
    const int fr = lane & 15, qtr = lane >> 4;
    const int bt = blockIdx.x >> 2, h = blockIdx.x & 3;

    // ---- V^T fragments: direct global -> register (chunk ^= dim&7 baked) ----
    const u16* gv = Xvt + ((size_t)bt * NHEAD + h) * 4096;
    f16x8 vf[2][4];
    #pragma unroll
    for (int kk = 0; kk < 2; ++kk) {
        int g = kk * 4 + qtr;
        #pragma unroll
        for (int mi = 0; mi < 4; ++mi) {
            int arow = mi * 16 + fr;
            vf[kk][mi] = *(const f16x8*)&gv[arow * 64 + ((g ^ (arow & 7)) << 3)];
        }
    }
    // ---- B-fragments for the score MFMA: 0.4*a, replicated rows ----
    f16x8 af[2];
    #pragma unroll
    for (int kk = 0; kk < 2; ++kk) {
        const float* ab = a + h * 64 + kk * 32 + qtr * 8;
        float4 a0 = *(const float4*)ab, a1 = *(const float4*)(ab + 4);
        af[kk][0] = (_Float16)(0.4f * a0.x); af[kk][1] = (_Float16)(0.4f * a0.y);
        af[kk][2] = (_Float16)(0.4f * a0.z); af[kk][3] = (_Float16)(0.4f * a0.w);
        af[kk][4] = (_Float16)(0.4f * a1.x); af[kk][5] = (_Float16)(0.4f * a1.y);
        af[kk][6] = (_Float16)(0.4f * a1.z); af[kk][7] = (_Float16)(0.4f * a1.w);
    }

    // ---- stage Q (already swizzled in global); zero P ----
    const u16* gq = Xqh + ((size_t)bt * NHEAD + h) * 4096;
    #pragma unroll
    for (int r = 0; r < 2; ++r) {
        int id = r * 256 + t;
        GLD16(gq + id * 8, (char*)sQ + id * 16);
    }
    #pragma unroll
    for (int i = 0; i < 4; ++i)
        ((float4*)sP)[t + i * 256] = make_float4(0.f, 0.f, 0.f, 0.f);
    __syncthreads();

    // ---- b[n] = <q_n, a>: 4 threads per node, 16 dims each (swizzled read) ----
    {
        int n = t >> 2, qq = t & 3;
        float b = 0.f;
        #pragma unroll
        for (int j = 0; j < 2; ++j) {
            int ck = qq * 2 + j;
            f16x8 qv = *(const f16x8*)&sQ[n * 64 + ((ck ^ (n & 7)) << 3)];
            const float* ab = a + h * 64 + ck * 8;
            float4 a0 = *(const float4*)ab, a1 = *(const float4*)(ab + 4);
            b = fmaf((float)qv[0], a0.x, b); b = fmaf((float)qv[1], a0.y, b);
            b = fmaf((float)qv[2], a0.z, b); b = fmaf((float)qv[3], a0.w, b);
            b = fmaf((float)qv[4], a1.x, b); b = fmaf((float)qv[5], a1.y, b);
            b = fmaf((float)qv[6], a1.z, b); b = fmaf((float)qv[7], a1.w, b);
        }
        b += __shfl_xor(b, 1);
        b += __shfl_xor(b, 2);
        if (qq == 0) sBn[n] = b;
    }
    __syncthreads();

    // ---- edge tables: sPack + hoisted linear term ----
    #pragma unroll
    for (int i = 0; i < 2; ++i) {
        int e = t + i * 256;
        int2 ge = gedge[e];
        int s_ = ge.x >> 8, d_ = ge.x & 255;
        sPack[e] = ge.x;
        sLin[e] = 0.6f * (sBn[s_] + sBn[d_]) + __int_as_float(ge.y);
    }
    __syncthreads();

    // ---- edge pass: 8 tiles/wave x 16 edges, scores via MFMA ----
    const int wbase = wave * 128;
    #pragma unroll
    for (int tt = 0; tt < 8; ++tt) {
        int e = wbase + tt * 16 + fr;
        int pk = sPack[e];
        int s_ = pk >> 8, d_ = pk & 255;
        f32x4 acc = 0.f;
        #pragma unroll
        for (int kk = 0; kk < 2; ++kk) {
            int ck = kk * 4 + qtr;
            f16x8 qs = *(const f16x8*)&sQ[s_ * 64 + ((ck ^ (s_ & 7)) << 3)];
            f16x8 qd = *(const f16x8*)&sQ[d_ * 64 + ((ck ^ (d_ & 7)) << 3)];
            f16x8 x = qs + qd;                       // 4x v_pk_add_f16
            unsigned xu[4];
            __builtin_memcpy(xu, &x, 16);
            xu[0] &= 0x7FFF7FFFu; xu[1] &= 0x7FFF7FFFu;
            xu[2] &= 0x7FFF7FFFu; xu[3] &= 0x7FFF7FFFu;
            f16x8 xa;
            __builtin_memcpy(&xa, xu, 16);
            acc = __builtin_amdgcn_mfma_f32_16x16x32_f16(xa, af[kk], acc, 0, 0, 0);
        }
        int c = lane & 15;
        if (c < 4) {
            float av = c == 0 ? acc[0] : c == 1 ? acc[1] : c == 2 ? acc[2] : acc[3];
            int eg = wbase + tt * 16 + qtr * 4 + c;
            int pk2 = sPack[eg];
            atomicAdd(&sP[(pk2 >> 8) * 64 + (pk2 & 255)], __expf(av + sLin[eg]));
        }
    }
    __syncthreads();

    // ---- convert: row-sum -> denom; normalize; fp16 into dead sQ (swizzled) ----
    {
        int s_ = t >> 2, qq = t & 3;
        const float4* row = (const float4*)&sP[s_ * 64 + qq * 16];
        float4 v0 = row[0], v1 = row[1], v2 = row[2], v3 = row[3];
        float part = v0.x + v0.y + v0.z + v0.w + v1.x + v1.y + v1.z + v1.w
                   + v2.x + v2.y + v2.z + v2.w + v3.x + v3.y + v3.z + v3.w;
        part += __shfl_xor(part, 1);
        part += __shfl_xor(part, 2);
        float inv = part > 0.f ? 1.f / part : 0.f;
        f16x2 p0 = pkrtz(v0.x * inv, v0.y * inv), p1 = pkrtz(v0.z * inv, v0.w * inv);
        f16x2 p2 = pkrtz(v1.x * inv, v1.y * inv), p3 = pkrtz(v1.z * inv, v1.w * inv);
        f16x2 p4 = pkrtz(v2.x * inv, v2.y * inv), p5 = pkrtz(v2.z * inv, v2.w * inv);
        f16x2 p6 = pkrtz(v3.x * inv, v3.y * inv), p7 = pkrtz(v3.z * inv, v3.w * inv);
        int c0 = qq * 2, c1 = qq * 2 + 1;
        u16* d0 = &sQ[s_ * 64 + ((c0 ^ (s_ & 7)) << 3)];
        u16* d1 = &sQ[s_ * 64 + ((c1 ^ (s_ & 7)) << 3)];
        ((f16x2*)d0)[0] = p0; ((f16x2*)d0)[1] = p1;
        ((f16x2*)d0)[2] = p2; ((f16x2*)d0)[3] = p3;
        ((f16x2*)d1)[0] = p4; ((f16x2*)d1)[1] = p5;
        ((f16x2*)d1)[2] = p6; ((f16x2*)d1)[3] = p7;
    }
    __syncthreads();

    // ---- Y^T = V^T · P^T : wave owns 16 src nodes; 8 MFMAs (A from regs) ----
    f32x4 acc[4];
    #pragma unroll
    for (int i = 0; i < 4; ++i) acc[i] = 0.f;
    const int srow = wave * 16 + fr;
    #pragma unroll
    for (int kk = 0; kk < 2; ++kk) {
        int g = kk * 4 + qtr;
        f16x8 fb = *(const f16x8*)&sQ[srow * 64 + ((g ^ (srow & 7)) << 3)];
        #pragma unroll
        for (int mi = 0; mi < 4; ++mi)
            acc[mi] = __builtin_amdgcn_mfma_f32_16x16x32_f16(vf[kk][mi], fb, acc[mi], 0, 0, 0);
    }

    // ---- store: col = src node, row = dim ----
    const int node = wave * 16 + fr;
    const int fq = qtr * 4;
    u16* yh = Yh + ((size_t)bt * NNODE + node) * D_ + h * 64;
    #pragma unroll
    for (int mi = 0; mi < 4; ++mi) {
        ushort4 v = make_ushort4(f2h(acc[mi][0]), f2h(acc[mi][1]),
                                 f2h(acc[mi][2]), f2h(acc[mi][3]));
        *(ushort4*)&yh[mi * 16 + fq] = v;
    }
}

// ---------------------------------------------------------------------------
extern "C" void kernel_launch(void* const* d_in, const int* in_sizes, int n_in,
                              void* d_out, int out_size, void* d_ws, size_t ws_size,
                              hipStream_t stream)
{
    const float* H     = (const float*)d_in[0];
    const float* W_lin = (const float*)d_in[1];
    const float* W_val = (const float*)d_in[2];
    const float* a     = (const float*)d_in[3];
    const float* W_out = (const float*)d_in[4];
    const float* A0    = (const float*)d_in[5];
    const int*   src   = (const int*)d_in[6];
    const int*   dst   = (const int*)d_in[7];

    const size_t nX = (size_t)BTN * D_;              // 16777216 elems
    // ws layout: Xqh [0,32M) | Yh [32M,64M) | Wqv 256K | Wouth 128K | gedge
    u16*  Xqh   = (u16*)d_ws;
    u16*  Yh    = Xqh + nX;
    u16*  Wqv   = Yh + nX;                           // 512 x 256 fp16
    u16*  Wouth = Wqv + 512 * D_;
    int2* gedge = (int2*)(Wouth + D_ * D_);
    if (ws_size < (size_t)134217728) return;

    u16* Xvt = (u16*)d_out;                          // d_out scratch until gemm3

    build_edge<<<1, 512, 0, stream>>>(src, dst, A0, gedge);
    prep_w3<<<192, 256, 0, stream>>>(W_lin, W_val, W_out,
                                     Wqv, Wqv + D_ * D_, Wouth);

    gemm12<<<2048, 256, 0, stream>>>(H, Wqv, Xqh, Xvt);

    fused_edge_agg<<<4096, 256, 0, stream>>>(Xqh, Xvt, gedge, a, Yh);

    gemm3<<<1024, 256, 0, stream>>>(Yh, Wouth, (float*)d_out);
}